// Round 5
// baseline (574.780 us; speedup 1.0000x reference)
//
#include <hip/hip_runtime.h>

// SOM layer on MI355X (gfx950).  R4 (resubmit; R4 bench was an infra timeout):
// 32 z-rows per wave (2 stripes) held in registers full-K (256 VGPRs), split
// fp16 hi/lo computed in the PROLOGUE (conv_z removed); p streams through
// double-buffered LDS (pre-split, pre-swizzled image from conv_p) with
// depth-1 prefetch. Each B-fragment read feeds 6 MFMAs -> per-CU LDS-read
// traffic halves vs R3 (was the bind). 4 waves/block, BM=128, grid 256
// (1 block/CU), __launch_bounds__(256,1) so the ~360-VGPR working set stays
// resident (R3's 108 VGPRs proved z was re-loaded from L2 every bi iter).
// Rank by s = p2[m] - 2*dot(z,p[m]); accuracy via 3-product split MFMA
// (hh+hl+lh) == fp32-GEMM precision (R1-R3: absmax 0.0).

#define N_ROWS 32768
#define M_PROTO 4096
#define DIM 512

typedef _Float16 half8 __attribute__((ext_vector_type(8)));
typedef _Float16 half4_t __attribute__((ext_vector_type(4)));
typedef float f32x4 __attribute__((ext_vector_type(4)));

__device__ __forceinline__ void gl_lds16(const void* g, void* l) {
    __builtin_amdgcn_global_load_lds(
        (const __attribute__((address_space(1))) unsigned int*)g,
        (__attribute__((address_space(3))) unsigned int*)l, 16, 0, 0);
}

// ---------------- p2[m] = sum(p[m][:]^2), fp32 ----------------
__global__ __launch_bounds__(256) void p2_kernel(const float* __restrict__ p,
                                                 float* __restrict__ p2) {
    const int w = threadIdx.x >> 6, l = threadIdx.x & 63;
    const int m = blockIdx.x * 4 + w;
    const float4* p4 = (const float4*)p + (size_t)m * 128;
    float s = 0.f;
#pragma unroll
    for (int i = 0; i < 2; ++i) {
        float4 v = p4[l * 2 + i];
        s += v.x * v.x + v.y * v.y + v.z * v.z + v.w * v.w;
    }
#pragma unroll
    for (int mm = 1; mm < 64; mm <<= 1) s += __shfl_xor(s, mm);
    if (l == 0) p2[m] = s;
}

// ---------------- conv_p: fp32 -> split fp16 pre-swizzled LDS-image tiles ----
// Tile = 128 rows x 64 k-halves (16 KB); addr = row*64 + (((kq>>1)^(row&7))<<3)
// + ((kq&1)<<2).  Tiles ordered tile = bi*8 + kt.
__global__ __launch_bounds__(256) void conv_p_kernel(const float* __restrict__ p,
                                                     _Float16* __restrict__ ph,
                                                     _Float16* __restrict__ pl) {
    const int tile = blockIdx.x;         // bi*8 + kt
    const int bi = tile >> 3, kt = tile & 7;
    const float4* p4 = (const float4*)p;
    const size_t tb = (size_t)tile * 8192;
#pragma unroll
    for (int it = 0; it < 8; ++it) {
        int q = it * 256 + threadIdx.x;
        int row = q >> 4, kq = q & 15;
        float4 v = p4[(size_t)(bi * 128 + row) * 128 + kt * 16 + kq];
        _Float16 h0 = (_Float16)v.x, h1 = (_Float16)v.y;
        _Float16 h2 = (_Float16)v.z, h3 = (_Float16)v.w;
        half4_t hv = {h0, h1, h2, h3};
        half4_t lv = {(_Float16)(v.x - (float)h0), (_Float16)(v.y - (float)h1),
                      (_Float16)(v.z - (float)h2), (_Float16)(v.w - (float)h3)};
        int addr = row * 64 + (((kq >> 1) ^ (row & 7)) << 3) + ((kq & 1) << 2);
        *(half4_t*)&ph[tb + addr] = hv;
        *(half4_t*)&pl[tb + addr] = lv;
    }
}

// ---------------- main: 32 z-rows/wave in regs, p dbuf-pipelined ------------
// 256 threads (4 waves). Wave w owns z-rows brow + w*32 .. +31 (stripes
// st=0,1), all 4096 cols. Per kt: 32 ds_read_b128 feed 96 MFMA (3 products x
// 2 stripes x 8 col-tiles x 2 k-slices); next p tile prefetched via
// global_load_lds into the other buffer (parity kt&1, compile-time).
__global__ __launch_bounds__(256, 1) void som_main(
    const float* __restrict__ z,
    const _Float16* __restrict__ ph, const _Float16* __restrict__ pl,
    const float* __restrict__ p2, const float* __restrict__ prot,
    float* __restrict__ out) {
    __shared__ __align__(16) _Float16 sPH[2][8192];
    __shared__ __align__(16) _Float16 sPL[2][8192];
    __shared__ int sFI[128];

    const int tid = threadIdx.x;
    const int w = tid >> 6, l = tid & 63;
    const int g = l >> 4, c = l & 15;
    const int blk = blockIdx.x, brow = blk * 128;

    // ---- prologue: load 32 z-rows, split into fp16 hi/lo regs (scaled -2) ----
    // A-frag: lane (g,c) holds A[row=c][k = ks*32 + g*8 + 0..7].
    half8 za[2][16], zb[2][16];
#pragma unroll
    for (int st = 0; st < 2; ++st) {
        const int rowg = brow + (w * 2 + st) * 16 + c;
        const float4* zr = (const float4*)z + (size_t)rowg * 128;
#pragma unroll
        for (int ks = 0; ks < 16; ++ks) {
            float4 v0 = zr[ks * 8 + g * 2 + 0];
            float4 v1 = zr[ks * 8 + g * 2 + 1];
            float x0 = -2.f * v0.x, x1 = -2.f * v0.y, x2 = -2.f * v0.z, x3 = -2.f * v0.w;
            float x4 = -2.f * v1.x, x5 = -2.f * v1.y, x6 = -2.f * v1.z, x7 = -2.f * v1.w;
            _Float16 h0 = (_Float16)x0, h1 = (_Float16)x1, h2 = (_Float16)x2, h3 = (_Float16)x3;
            _Float16 h4 = (_Float16)x4, h5 = (_Float16)x5, h6 = (_Float16)x6, h7 = (_Float16)x7;
            half8 hv = {h0, h1, h2, h3, h4, h5, h6, h7};
            half8 lv = {(_Float16)(x0 - (float)h0), (_Float16)(x1 - (float)h1),
                        (_Float16)(x2 - (float)h2), (_Float16)(x3 - (float)h3),
                        (_Float16)(x4 - (float)h4), (_Float16)(x5 - (float)h5),
                        (_Float16)(x6 - (float)h6), (_Float16)(x7 - (float)h7)};
            za[st][ks] = hv;
            zb[st][ks] = lv;
        }
    }

    // ---- stage p tile 0 into buffer 0 ----
#pragma unroll
    for (int j = 0; j < 4; ++j) {
        const int off = j * 2048 + tid * 8;   // halves; lane-contiguous 16B
        gl_lds16(ph + off, &sPH[0][off]);
        gl_lds16(pl + off, &sPL[0][off]);
    }
    __syncthreads();

    float minv[2][4];
    int mini[2][4];
#pragma unroll
    for (int st = 0; st < 2; ++st)
#pragma unroll
        for (int r = 0; r < 4; ++r) { minv[st][r] = 3.0e38f; mini[st][r] = 0; }

    for (int bi = 0; bi < 32; ++bi) {
        f32x4 acc[2][8];
#pragma unroll
        for (int st = 0; st < 2; ++st)
#pragma unroll
            for (int jt = 0; jt < 8; ++jt) acc[st][jt] = (f32x4){0.f, 0.f, 0.f, 0.f};

#pragma unroll
        for (int kt = 0; kt < 8; ++kt) {
            const int cur = kt & 1;            // bi*8 even => parity is kt&1
            const int tp = bi * 8 + kt;
            // ---- prefetch next tile into the other buffer ----
            if (tp < 255) {
                const _Float16* sph = ph + (size_t)(tp + 1) * 8192;
                const _Float16* spl = pl + (size_t)(tp + 1) * 8192;
#pragma unroll
                for (int j = 0; j < 4; ++j) {
                    const int off = j * 2048 + tid * 8;
                    gl_lds16(sph + off, &sPH[cur ^ 1][off]);
                    gl_lds16(spl + off, &sPL[cur ^ 1][off]);
                }
            }
            // ---- compute: 2 k-slices x (16 ds_read_b128 + 48 MFMA) ----
#pragma unroll
            for (int ksl = 0; ksl < 2; ++ksl) {
                const int ks = kt * 2 + ksl;
#pragma unroll
                for (int jt = 0; jt < 8; ++jt) {
                    const int row = jt * 16 + c;
                    const int addr = row * 64 + (((ksl * 4 + g) ^ (row & 7)) << 3);
                    half8 bh = *(half8*)&sPH[cur][addr];
                    half8 bl = *(half8*)&sPL[cur][addr];
#pragma unroll
                    for (int st = 0; st < 2; ++st) {
                        acc[st][jt] = __builtin_amdgcn_mfma_f32_16x16x32_f16(za[st][ks], bh, acc[st][jt], 0, 0, 0);
                        acc[st][jt] = __builtin_amdgcn_mfma_f32_16x16x32_f16(za[st][ks], bl, acc[st][jt], 0, 0, 0);
                        acc[st][jt] = __builtin_amdgcn_mfma_f32_16x16x32_f16(zb[st][ks], bh, acc[st][jt], 0, 0, 0);
                    }
                }
            }
            __syncthreads();  // drains prefetch (vmcnt) + reads (lgkm)
        }

        // ---- epilogue: s = acc + p2[col]; running (min, idx) ----
#pragma unroll
        for (int jt = 0; jt < 8; ++jt) {
            const int colg = bi * 128 + jt * 16 + c;
            float pv = p2[colg];
#pragma unroll
            for (int st = 0; st < 2; ++st)
#pragma unroll
                for (int r = 0; r < 4; ++r) {
                    float s = acc[st][jt][r] + pv;
                    if (s < minv[st][r] || (s == minv[st][r] && colg < mini[st][r])) {
                        minv[st][r] = s;
                        mini[st][r] = colg;
                    }
                }
        }
    }

    // ---- cross-lane reduce over the 16 col-slots (c); rows are (st,g,r) ----
#pragma unroll
    for (int st = 0; st < 2; ++st)
#pragma unroll
        for (int r = 0; r < 4; ++r) {
            float v = minv[st][r];
            int id = mini[st][r];
#pragma unroll
            for (int mm = 1; mm < 16; mm <<= 1) {
                float ov = __shfl_xor(v, mm);
                int oi = __shfl_xor(id, mm);
                if (ov < v || (ov == v && oi < id)) { v = ov; id = oi; }
            }
            if (c == 0) {
                const int rl = (w * 2 + st) * 16 + g * 4 + r;  // local row 0..127
                sFI[rl] = id;
                out[(size_t)N_ROWS * DIM + brow + rl] = (float)id;
            }
        }
    __syncthreads();

    // ---- winner prototype copy: 128 rows x 128 float4 ----
    const float4* pr4 = (const float4*)prot;
    float4* out4 = (float4*)out;
#pragma unroll 4
    for (int it = 0; it < 64; ++it) {
        const int q = it * 256 + tid;
        const int row = q >> 7, qk = q & 127;
        const int fi = sFI[row];
        out4[(size_t)(brow + row) * 128 + qk] = pr4[(size_t)fi * 128 + qk];
    }
}

// ---------------- fallback (R1 kernel, used only if ws too small) -----------
__global__ __launch_bounds__(256) void som_fallback(const float* __restrict__ z,
                                                    const float* __restrict__ prot,
                                                    const float* __restrict__ p2,
                                                    float* __restrict__ out) {
    __shared__ __align__(16) _Float16 sZH[64 * 64];
    __shared__ __align__(16) _Float16 sZL[64 * 64];
    __shared__ __align__(16) _Float16 sPH[128 * 64];
    __shared__ __align__(16) _Float16 sPL[128 * 64];
    __shared__ float sMV[4][64];
    __shared__ int sMI[4][64];
    __shared__ int sFI[64];

    const int tid = threadIdx.x;
    const int w = tid >> 6, l = tid & 63;
    const int g = l >> 4, c = l & 15;
    const int brow = blockIdx.x * 64;
    const float4* z4 = (const float4*)z;
    const float4* pr4 = (const float4*)prot;

    float minv[4][4];
    int mini[4][4];
#pragma unroll
    for (int i = 0; i < 4; ++i)
#pragma unroll
        for (int r = 0; r < 4; ++r) { minv[i][r] = 3.0e38f; mini[i][r] = 0; }

    for (int bcol = 0; bcol < M_PROTO; bcol += 128) {
        f32x4 acc[4][2];
#pragma unroll
        for (int i = 0; i < 4; ++i)
#pragma unroll
            for (int jt = 0; jt < 2; ++jt) acc[i][jt] = (f32x4){0.f, 0.f, 0.f, 0.f};
        for (int kt = 0; kt < 8; ++kt) {
            __syncthreads();
#pragma unroll
            for (int it = 0; it < 4; ++it) {
                int q = it * 256 + tid;
                int row = q >> 4, kq = q & 15;
                float4 v = z4[(size_t)(brow + row) * 128 + kt * 16 + kq];
                float x0 = -2.f * v.x, x1 = -2.f * v.y, x2 = -2.f * v.z, x3 = -2.f * v.w;
                _Float16 h0 = (_Float16)x0, h1 = (_Float16)x1;
                _Float16 h2 = (_Float16)x2, h3 = (_Float16)x3;
                half4_t hv = {h0, h1, h2, h3};
                half4_t lv = {(_Float16)(x0 - (float)h0), (_Float16)(x1 - (float)h1),
                              (_Float16)(x2 - (float)h2), (_Float16)(x3 - (float)h3)};
                int addr = row * 64 + (((kq >> 1) ^ (row & 7)) << 3) + ((kq & 1) << 2);
                *(half4_t*)&sZH[addr] = hv;
                *(half4_t*)&sZL[addr] = lv;
            }
#pragma unroll
            for (int it = 0; it < 8; ++it) {
                int q = it * 256 + tid;
                int row = q >> 4, kq = q & 15;
                float4 v = pr4[(size_t)(bcol + row) * 128 + kt * 16 + kq];
                _Float16 h0 = (_Float16)v.x, h1 = (_Float16)v.y;
                _Float16 h2 = (_Float16)v.z, h3 = (_Float16)v.w;
                half4_t hv = {h0, h1, h2, h3};
                half4_t lv = {(_Float16)(v.x - (float)h0), (_Float16)(v.y - (float)h1),
                              (_Float16)(v.z - (float)h2), (_Float16)(v.w - (float)h3)};
                int addr = row * 64 + (((kq >> 1) ^ (row & 7)) << 3) + ((kq & 1) << 2);
                *(half4_t*)&sPH[addr] = hv;
                *(half4_t*)&sPL[addr] = lv;
            }
            __syncthreads();
#pragma unroll
            for (int ks = 0; ks < 2; ++ks) {
                half8 ah[4], al[4], bh[2], bl[2];
#pragma unroll
                for (int i = 0; i < 4; ++i) {
                    int row = i * 16 + c;
                    int addr = row * 64 + (((ks * 4 + g) ^ (row & 7)) << 3);
                    ah[i] = *(half8*)&sZH[addr];
                    al[i] = *(half8*)&sZL[addr];
                }
#pragma unroll
                for (int jt = 0; jt < 2; ++jt) {
                    int row = w * 32 + jt * 16 + c;
                    int addr = row * 64 + (((ks * 4 + g) ^ (row & 7)) << 3);
                    bh[jt] = *(half8*)&sPH[addr];
                    bl[jt] = *(half8*)&sPL[addr];
                }
#pragma unroll
                for (int i = 0; i < 4; ++i)
#pragma unroll
                    for (int jt = 0; jt < 2; ++jt) {
                        acc[i][jt] = __builtin_amdgcn_mfma_f32_16x16x32_f16(ah[i], bh[jt], acc[i][jt], 0, 0, 0);
                        acc[i][jt] = __builtin_amdgcn_mfma_f32_16x16x32_f16(ah[i], bl[jt], acc[i][jt], 0, 0, 0);
                        acc[i][jt] = __builtin_amdgcn_mfma_f32_16x16x32_f16(al[i], bh[jt], acc[i][jt], 0, 0, 0);
                    }
            }
        }
#pragma unroll
        for (int jt = 0; jt < 2; ++jt) {
            int colg = bcol + w * 32 + jt * 16 + c;
            float pv = p2[colg];
#pragma unroll
            for (int i = 0; i < 4; ++i)
#pragma unroll
                for (int r = 0; r < 4; ++r) {
                    float s = acc[i][jt][r] + pv;
                    if (s < minv[i][r] || (s == minv[i][r] && colg < mini[i][r])) {
                        minv[i][r] = s;
                        mini[i][r] = colg;
                    }
                }
        }
    }
#pragma unroll
    for (int i = 0; i < 4; ++i)
#pragma unroll
        for (int r = 0; r < 4; ++r) {
            float v = minv[i][r];
            int id = mini[i][r];
#pragma unroll
            for (int mm = 1; mm < 16; mm <<= 1) {
                float ov = __shfl_xor(v, mm);
                int oi = __shfl_xor(id, mm);
                if (ov < v || (ov == v && oi < id)) { v = ov; id = oi; }
            }
            if (c == 0) {
                sMV[w][i * 16 + g * 4 + r] = v;
                sMI[w][i * 16 + g * 4 + r] = id;
            }
        }
    __syncthreads();
    if (tid < 64) {
        float v = sMV[0][tid];
        int id = sMI[0][tid];
#pragma unroll
        for (int ww = 1; ww < 4; ++ww) {
            float ov = sMV[ww][tid];
            int oi = sMI[ww][tid];
            if (ov < v || (ov == v && oi < id)) { v = ov; id = oi; }
        }
        sFI[tid] = id;
        out[(size_t)N_ROWS * DIM + brow + tid] = (float)id;
    }
    __syncthreads();
    float4* out4 = (float4*)out;
#pragma unroll 4
    for (int it = 0; it < 32; ++it) {
        int q = it * 256 + tid;
        int row = q >> 7, qk = q & 127;
        int fi = sFI[row];
        out4[(size_t)(brow + row) * 128 + qk] = pr4[(size_t)fi * 128 + qk];
    }
}

extern "C" void kernel_launch(void* const* d_in, const int* in_sizes, int n_in,
                              void* d_out, int out_size, void* d_ws, size_t ws_size,
                              hipStream_t stream) {
    const float* z = (const float*)d_in[0];
    const float* prot = (const float*)d_in[1];
    char* base = (char*)d_ws;
    float* p2 = (float*)base;  // 16 KB

    const size_t NEED = 16384 + 8388608;  // p2 + ph/pl images

    p2_kernel<<<M_PROTO / 4, 256, 0, stream>>>(prot, p2);

    if (ws_size >= NEED) {
        _Float16* ph = (_Float16*)(base + 16384);
        _Float16* pl = (_Float16*)(base + 16384 + 4194304);
        conv_p_kernel<<<256, 256, 0, stream>>>(prot, ph, pl);
        som_main<<<N_ROWS / 128, 256, 0, stream>>>(z, ph, pl, p2, prot, (float*)d_out);
    } else {
        som_fallback<<<N_ROWS / 64, 256, 0, stream>>>(z, prot, p2, (float*)d_out);
    }
}

// Round 6
// 565.536 us; speedup vs baseline: 1.0163x; 1.0163x over previous
//
#include <hip/hip_runtime.h>

// SOM layer on MI355X (gfx950).  R5: R4 structure + T4 counted-vmcnt pipeline.
// p streams through a 4-buffer LDS ring (depth-2 prefetch); per K-step the
// wave waits s_waitcnt vmcnt(16) (never 0 in steady state) + raw s_barrier +
// sched_barrier(0) instead of __syncthreads -- prefetched tiles stay in
// flight across barriers (the vmcnt(0) drain was R4's serializer).
// 32 z-rows per wave split fp16 hi/lo in the prologue; 4 waves/block, BM=128,
// grid 256, 1 block/CU. Rank by s = p2[m] - 2*dot(z,p[m]); accuracy via
// 3-product split MFMA (hh+hl+lh) == fp32-GEMM precision (R1-R4: absmax 0.0).

#define N_ROWS 32768
#define M_PROTO 4096
#define DIM 512

typedef _Float16 half8 __attribute__((ext_vector_type(8)));
typedef _Float16 half4_t __attribute__((ext_vector_type(4)));
typedef float f32x4 __attribute__((ext_vector_type(4)));

__device__ __forceinline__ void gl_lds16(const void* g, void* l) {
    __builtin_amdgcn_global_load_lds(
        (const __attribute__((address_space(1))) unsigned int*)g,
        (__attribute__((address_space(3))) unsigned int*)l, 16, 0, 0);
}

#define WAITV(N) asm volatile("s_waitcnt vmcnt(" #N ")" ::: "memory")

// ---------------- p2[m] = sum(p[m][:]^2), fp32 ----------------
__global__ __launch_bounds__(256) void p2_kernel(const float* __restrict__ p,
                                                 float* __restrict__ p2) {
    const int w = threadIdx.x >> 6, l = threadIdx.x & 63;
    const int m = blockIdx.x * 4 + w;
    const float4* p4 = (const float4*)p + (size_t)m * 128;
    float s = 0.f;
#pragma unroll
    for (int i = 0; i < 2; ++i) {
        float4 v = p4[l * 2 + i];
        s += v.x * v.x + v.y * v.y + v.z * v.z + v.w * v.w;
    }
#pragma unroll
    for (int mm = 1; mm < 64; mm <<= 1) s += __shfl_xor(s, mm);
    if (l == 0) p2[m] = s;
}

// ---------------- conv_p: fp32 -> split fp16 pre-swizzled LDS-image tiles ----
// Tile = 128 rows x 64 k-halves (16 KB); addr = row*64 + (((kq>>1)^(row&7))<<3)
// + ((kq&1)<<2).  Tiles ordered tile = bi*8 + kt.
__global__ __launch_bounds__(256) void conv_p_kernel(const float* __restrict__ p,
                                                     _Float16* __restrict__ ph,
                                                     _Float16* __restrict__ pl) {
    const int tile = blockIdx.x;         // bi*8 + kt
    const int bi = tile >> 3, kt = tile & 7;
    const float4* p4 = (const float4*)p;
    const size_t tb = (size_t)tile * 8192;
#pragma unroll
    for (int it = 0; it < 8; ++it) {
        int q = it * 256 + threadIdx.x;
        int row = q >> 4, kq = q & 15;
        float4 v = p4[(size_t)(bi * 128 + row) * 128 + kt * 16 + kq];
        _Float16 h0 = (_Float16)v.x, h1 = (_Float16)v.y;
        _Float16 h2 = (_Float16)v.z, h3 = (_Float16)v.w;
        half4_t hv = {h0, h1, h2, h3};
        half4_t lv = {(_Float16)(v.x - (float)h0), (_Float16)(v.y - (float)h1),
                      (_Float16)(v.z - (float)h2), (_Float16)(v.w - (float)h3)};
        int addr = row * 64 + (((kq >> 1) ^ (row & 7)) << 3) + ((kq & 1) << 2);
        *(half4_t*)&ph[tb + addr] = hv;
        *(half4_t*)&pl[tb + addr] = lv;
    }
}

// ---------------- main: 32 z-rows/wave in regs, p in 4-buffer LDS ring ------
// 256 threads (4 waves). Wave w owns z-rows brow + w*32 .. +31, all 4096 cols.
// Tile tp = bi*8+kt lives in buffer tp&3 (= kt&3, compile-time). Depth-2
// prefetch: iter tp issues STAGE(tp+2); waits vmcnt(16) (own tile-tp loads
// done, 16 younger stay in flight); s_barrier; compute.
__global__ __launch_bounds__(256, 1) void som_main(
    const float* __restrict__ z,
    const _Float16* __restrict__ ph, const _Float16* __restrict__ pl,
    const float* __restrict__ p2, const float* __restrict__ prot,
    float* __restrict__ out) {
    __shared__ __align__(16) _Float16 sPH[4][8192];
    __shared__ __align__(16) _Float16 sPL[4][8192];
    __shared__ int sFI[128];

    const int tid = threadIdx.x;
    const int w = tid >> 6, l = tid & 63;
    const int g = l >> 4, c = l & 15;
    const int blk = blockIdx.x, brow = blk * 128;

    // ---- prologue: load 32 z-rows, split into fp16 hi/lo regs (scaled -2) ----
    // A-frag: lane (g,c) holds A[row=c][k = ks*32 + g*8 + 0..7].
    half8 za[2][16], zb[2][16];
#pragma unroll
    for (int st = 0; st < 2; ++st) {
        const int rowg = brow + (w * 2 + st) * 16 + c;
        const float4* zr = (const float4*)z + (size_t)rowg * 128;
#pragma unroll
        for (int ks = 0; ks < 16; ++ks) {
            float4 v0 = zr[ks * 8 + g * 2 + 0];
            float4 v1 = zr[ks * 8 + g * 2 + 1];
            float x0 = -2.f * v0.x, x1 = -2.f * v0.y, x2 = -2.f * v0.z, x3 = -2.f * v0.w;
            float x4 = -2.f * v1.x, x5 = -2.f * v1.y, x6 = -2.f * v1.z, x7 = -2.f * v1.w;
            _Float16 h0 = (_Float16)x0, h1 = (_Float16)x1, h2 = (_Float16)x2, h3 = (_Float16)x3;
            _Float16 h4 = (_Float16)x4, h5 = (_Float16)x5, h6 = (_Float16)x6, h7 = (_Float16)x7;
            half8 hv = {h0, h1, h2, h3, h4, h5, h6, h7};
            half8 lv = {(_Float16)(x0 - (float)h0), (_Float16)(x1 - (float)h1),
                        (_Float16)(x2 - (float)h2), (_Float16)(x3 - (float)h3),
                        (_Float16)(x4 - (float)h4), (_Float16)(x5 - (float)h5),
                        (_Float16)(x6 - (float)h6), (_Float16)(x7 - (float)h7)};
            za[st][ks] = hv;
            zb[st][ks] = lv;
        }
    }

    // ---- prologue: stage tiles 0 and 1 into ring buffers 0,1 (16 in flight) ----
#pragma unroll
    for (int t0 = 0; t0 < 2; ++t0) {
        const _Float16* sph = ph + (size_t)t0 * 8192;
        const _Float16* spl = pl + (size_t)t0 * 8192;
#pragma unroll
        for (int j = 0; j < 4; ++j) {
            const int off = j * 2048 + tid * 8;   // halves; lane-contiguous 16B
            gl_lds16(sph + off, &sPH[t0][off]);
            gl_lds16(spl + off, &sPL[t0][off]);
        }
    }

    float minv[2][4];
    int mini[2][4];
#pragma unroll
    for (int st = 0; st < 2; ++st)
#pragma unroll
        for (int r = 0; r < 4; ++r) { minv[st][r] = 3.0e38f; mini[st][r] = 0; }

    for (int bi = 0; bi < 32; ++bi) {
        f32x4 acc[2][8];
#pragma unroll
        for (int st = 0; st < 2; ++st)
#pragma unroll
            for (int jt = 0; jt < 8; ++jt) acc[st][jt] = (f32x4){0.f, 0.f, 0.f, 0.f};

#pragma unroll
        for (int kt = 0; kt < 8; ++kt) {
            const int tp = bi * 8 + kt;
            const int cb = kt & 3;            // tile tp's buffer (bi*8 ≡ 0 mod 4)
            const int nb = (kt + 2) & 3;      // stage target for tp+2
            // ---- issue depth-2 prefetch ----
            if (tp + 2 < 256) {
                const _Float16* sph = ph + (size_t)(tp + 2) * 8192;
                const _Float16* spl = pl + (size_t)(tp + 2) * 8192;
#pragma unroll
                for (int j = 0; j < 4; ++j) {
                    const int off = j * 2048 + tid * 8;
                    gl_lds16(sph + off, &sPH[nb][off]);
                    gl_lds16(spl + off, &sPL[nb][off]);
                }
            }
            // ---- counted wait: own tile-tp loads done; younger stay in flight ----
            if (kt < 6) {
                WAITV(16);
            } else if (kt == 6) {
                if (bi < 31) { WAITV(16); } else { WAITV(8); }
            } else {
                if (bi < 31) { WAITV(16); } else { WAITV(0); }
            }
            __builtin_amdgcn_s_barrier();
            __builtin_amdgcn_sched_barrier(0);  // keep ds_reads below the barrier

            // ---- compute tile tp: 2 k-slices x (16 ds_read_b128 + 48 MFMA) ----
#pragma unroll
            for (int ksl = 0; ksl < 2; ++ksl) {
                const int ks = kt * 2 + ksl;
#pragma unroll
                for (int jt = 0; jt < 8; ++jt) {
                    const int row = jt * 16 + c;
                    const int addr = row * 64 + (((ksl * 4 + g) ^ (row & 7)) << 3);
                    half8 bh = *(half8*)&sPH[cb][addr];
                    half8 bl = *(half8*)&sPL[cb][addr];
#pragma unroll
                    for (int st = 0; st < 2; ++st) {
                        acc[st][jt] = __builtin_amdgcn_mfma_f32_16x16x32_f16(za[st][ks], bh, acc[st][jt], 0, 0, 0);
                        acc[st][jt] = __builtin_amdgcn_mfma_f32_16x16x32_f16(za[st][ks], bl, acc[st][jt], 0, 0, 0);
                        acc[st][jt] = __builtin_amdgcn_mfma_f32_16x16x32_f16(zb[st][ks], bh, acc[st][jt], 0, 0, 0);
                    }
                }
            }
        }

        // ---- epilogue: s = acc + p2[col]; running (min, idx) ----
#pragma unroll
        for (int jt = 0; jt < 8; ++jt) {
            const int colg = bi * 128 + jt * 16 + c;
            float pv = p2[colg];
#pragma unroll
            for (int st = 0; st < 2; ++st)
#pragma unroll
                for (int r = 0; r < 4; ++r) {
                    float s = acc[st][jt][r] + pv;
                    if (s < minv[st][r] || (s == minv[st][r] && colg < mini[st][r])) {
                        minv[st][r] = s;
                        mini[st][r] = colg;
                    }
                }
        }
    }

    // ---- cross-lane reduce over the 16 col-slots (c); rows are (st,g,r) ----
#pragma unroll
    for (int st = 0; st < 2; ++st)
#pragma unroll
        for (int r = 0; r < 4; ++r) {
            float v = minv[st][r];
            int id = mini[st][r];
#pragma unroll
            for (int mm = 1; mm < 16; mm <<= 1) {
                float ov = __shfl_xor(v, mm);
                int oi = __shfl_xor(id, mm);
                if (ov < v || (ov == v && oi < id)) { v = ov; id = oi; }
            }
            if (c == 0) {
                const int rl = (w * 2 + st) * 16 + g * 4 + r;  // local row 0..127
                sFI[rl] = id;
                out[(size_t)N_ROWS * DIM + brow + rl] = (float)id;
            }
        }
    __syncthreads();

    // ---- winner prototype copy: 128 rows x 128 float4 ----
    const float4* pr4 = (const float4*)prot;
    float4* out4 = (float4*)out;
#pragma unroll 4
    for (int it = 0; it < 64; ++it) {
        const int q = it * 256 + tid;
        const int row = q >> 7, qk = q & 127;
        const int fi = sFI[row];
        out4[(size_t)(brow + row) * 128 + qk] = pr4[(size_t)fi * 128 + qk];
    }
}

// ---------------- fallback (R1 kernel, used only if ws too small) -----------
__global__ __launch_bounds__(256) void som_fallback(const float* __restrict__ z,
                                                    const float* __restrict__ prot,
                                                    const float* __restrict__ p2,
                                                    float* __restrict__ out) {
    __shared__ __align__(16) _Float16 sZH[64 * 64];
    __shared__ __align__(16) _Float16 sZL[64 * 64];
    __shared__ __align__(16) _Float16 sPH[128 * 64];
    __shared__ __align__(16) _Float16 sPL[128 * 64];
    __shared__ float sMV[4][64];
    __shared__ int sMI[4][64];
    __shared__ int sFI[64];

    const int tid = threadIdx.x;
    const int w = tid >> 6, l = tid & 63;
    const int g = l >> 4, c = l & 15;
    const int brow = blockIdx.x * 64;
    const float4* z4 = (const float4*)z;
    const float4* pr4 = (const float4*)prot;

    float minv[4][4];
    int mini[4][4];
#pragma unroll
    for (int i = 0; i < 4; ++i)
#pragma unroll
        for (int r = 0; r < 4; ++r) { minv[i][r] = 3.0e38f; mini[i][r] = 0; }

    for (int bcol = 0; bcol < M_PROTO; bcol += 128) {
        f32x4 acc[4][2];
#pragma unroll
        for (int i = 0; i < 4; ++i)
#pragma unroll
            for (int jt = 0; jt < 2; ++jt) acc[i][jt] = (f32x4){0.f, 0.f, 0.f, 0.f};
        for (int kt = 0; kt < 8; ++kt) {
            __syncthreads();
#pragma unroll
            for (int it = 0; it < 4; ++it) {
                int q = it * 256 + tid;
                int row = q >> 4, kq = q & 15;
                float4 v = z4[(size_t)(brow + row) * 128 + kt * 16 + kq];
                float x0 = -2.f * v.x, x1 = -2.f * v.y, x2 = -2.f * v.z, x3 = -2.f * v.w;
                _Float16 h0 = (_Float16)x0, h1 = (_Float16)x1;
                _Float16 h2 = (_Float16)x2, h3 = (_Float16)x3;
                half4_t hv = {h0, h1, h2, h3};
                half4_t lv = {(_Float16)(x0 - (float)h0), (_Float16)(x1 - (float)h1),
                              (_Float16)(x2 - (float)h2), (_Float16)(x3 - (float)h3)};
                int addr = row * 64 + (((kq >> 1) ^ (row & 7)) << 3) + ((kq & 1) << 2);
                *(half4_t*)&sZH[addr] = hv;
                *(half4_t*)&sZL[addr] = lv;
            }
#pragma unroll
            for (int it = 0; it < 8; ++it) {
                int q = it * 256 + tid;
                int row = q >> 4, kq = q & 15;
                float4 v = pr4[(size_t)(bcol + row) * 128 + kt * 16 + kq];
                _Float16 h0 = (_Float16)v.x, h1 = (_Float16)v.y;
                _Float16 h2 = (_Float16)v.z, h3 = (_Float16)v.w;
                half4_t hv = {h0, h1, h2, h3};
                half4_t lv = {(_Float16)(v.x - (float)h0), (_Float16)(v.y - (float)h1),
                              (_Float16)(v.z - (float)h2), (_Float16)(v.w - (float)h3)};
                int addr = row * 64 + (((kq >> 1) ^ (row & 7)) << 3) + ((kq & 1) << 2);
                *(half4_t*)&sPH[addr] = hv;
                *(half4_t*)&sPL[addr] = lv;
            }
            __syncthreads();
#pragma unroll
            for (int ks = 0; ks < 2; ++ks) {
                half8 ah[4], al[4], bh[2], bl[2];
#pragma unroll
                for (int i = 0; i < 4; ++i) {
                    int row = i * 16 + c;
                    int addr = row * 64 + (((ks * 4 + g) ^ (row & 7)) << 3);
                    ah[i] = *(half8*)&sZH[addr];
                    al[i] = *(half8*)&sZL[addr];
                }
#pragma unroll
                for (int jt = 0; jt < 2; ++jt) {
                    int row = w * 32 + jt * 16 + c;
                    int addr = row * 64 + (((ks * 4 + g) ^ (row & 7)) << 3);
                    bh[jt] = *(half8*)&sPH[addr];
                    bl[jt] = *(half8*)&sPL[addr];
                }
#pragma unroll
                for (int i = 0; i < 4; ++i)
#pragma unroll
                    for (int jt = 0; jt < 2; ++jt) {
                        acc[i][jt] = __builtin_amdgcn_mfma_f32_16x16x32_f16(ah[i], bh[jt], acc[i][jt], 0, 0, 0);
                        acc[i][jt] = __builtin_amdgcn_mfma_f32_16x16x32_f16(ah[i], bl[jt], acc[i][jt], 0, 0, 0);
                        acc[i][jt] = __builtin_amdgcn_mfma_f32_16x16x32_f16(al[i], bh[jt], acc[i][jt], 0, 0, 0);
                    }
            }
        }
#pragma unroll
        for (int jt = 0; jt < 2; ++jt) {
            int colg = bcol + w * 32 + jt * 16 + c;
            float pv = p2[colg];
#pragma unroll
            for (int i = 0; i < 4; ++i)
#pragma unroll
                for (int r = 0; r < 4; ++r) {
                    float s = acc[i][jt][r] + pv;
                    if (s < minv[i][r] || (s == minv[i][r] && colg < mini[i][r])) {
                        minv[i][r] = s;
                        mini[i][r] = colg;
                    }
                }
        }
    }
#pragma unroll
    for (int i = 0; i < 4; ++i)
#pragma unroll
        for (int r = 0; r < 4; ++r) {
            float v = minv[i][r];
            int id = mini[i][r];
#pragma unroll
            for (int mm = 1; mm < 16; mm <<= 1) {
                float ov = __shfl_xor(v, mm);
                int oi = __shfl_xor(id, mm);
                if (ov < v || (ov == v && oi < id)) { v = ov; id = oi; }
            }
            if (c == 0) {
                sMV[w][i * 16 + g * 4 + r] = v;
                sMI[w][i * 16 + g * 4 + r] = id;
            }
        }
    __syncthreads();
    if (tid < 64) {
        float v = sMV[0][tid];
        int id = sMI[0][tid];
#pragma unroll
        for (int ww = 1; ww < 4; ++ww) {
            float ov = sMV[ww][tid];
            int oi = sMI[ww][tid];
            if (ov < v || (ov == v && oi < id)) { v = ov; id = oi; }
        }
        sFI[tid] = id;
        out[(size_t)N_ROWS * DIM + brow + tid] = (float)id;
    }
    __syncthreads();
    float4* out4 = (float4*)out;
#pragma unroll 4
    for (int it = 0; it < 32; ++it) {
        int q = it * 256 + tid;
        int row = q >> 7, qk = q & 127;
        int fi = sFI[row];
        out4[(size_t)(brow + row) * 128 + qk] = pr4[(size_t)fi * 128 + qk];
    }
}

extern "C" void kernel_launch(void* const* d_in, const int* in_sizes, int n_in,
                              void* d_out, int out_size, void* d_ws, size_t ws_size,
                              hipStream_t stream) {
    const float* z = (const float*)d_in[0];
    const float* prot = (const float*)d_in[1];
    char* base = (char*)d_ws;
    float* p2 = (float*)base;  // 16 KB

    const size_t NEED = 16384 + 8388608;  // p2 + ph/pl images

    p2_kernel<<<M_PROTO / 4, 256, 0, stream>>>(prot, p2);

    if (ws_size >= NEED) {
        _Float16* ph = (_Float16*)(base + 16384);
        _Float16* pl = (_Float16*)(base + 16384 + 4194304);
        conv_p_kernel<<<256, 256, 0, stream>>>(prot, ph, pl);
        som_main<<<N_ROWS / 128, 256, 0, stream>>>(z, ph, pl, p2, prot, (float*)d_out);
    } else {
        som_fallback<<<N_ROWS / 64, 256, 0, stream>>>(z, prot, p2, (float*)d_out);
    }
}